// Round 1
// 1329.936 us; speedup vs baseline: 1.0031x; 1.0031x over previous
//
#include <hip/hip_runtime.h>
#include <hip/hip_fp16.h>

#define USER_NUM 200000
#define ITEM_NUM 100000
#define N_NODES  300000   // USER_NUM + ITEM_NUM
#define N_EDGES  9600000
#define D        64
#define NELEM    ((long long)N_NODES * D)       // 19,200,000
#define NELEM4   (NELEM / 4)                    // 4,800,000

// Fixed-capacity bucket per node. deg ~ Poisson(32), max for this dataset
// ~60; CAP=96 leaves huge margin (clamp guard below makes OOB impossible).
#define CAP 96

// Slot entry packing: [31:19] = 13-bit weight q (w = q/8191), [18:0] = src id.
#define SRC_MASK 0x7FFFFu
#define W_SCALE  (1.0f / 8191.0f)

// ---- binned bucket-build geometry ----
// 586 bins of 512 nodes. Pass A bins edges with LDS histograms (one global
// atomic per block x bin instead of per edge); Pass B fills slot buckets with
// LDS deg counters and L2-resident scattered stores (bin slot region = 192 KB
// << 4 MB per-XCD L2), eliminating the 16x partial-line write amplification
// the single-pass atomic fill showed (WRITE_SIZE 590 MB for 38 MB of data).
#define BIN_NODES 512
#define BIN_SHIFT 9
#define NBINS     ((N_NODES + BIN_NODES - 1) / BIN_NODES)   // 586
#define BIN_CAP   17408   // per-bin segment cap; mean 16384, sigma 128 (+8s)
#define EPB       8192    // edges per block in pass A
#define NBLK_A    ((N_EDGES + EPB - 1) / EPB)               // 1172

// ---------------------------------------------------------------- init
// out = all_emb (fp32), cur = fp16(all_emb). 4 elements/thread.
__global__ void init_kernel(const float4* __restrict__ user_emb,
                            const float4* __restrict__ item_emb,
                            float4* __restrict__ out,
                            ushort4* __restrict__ cur) {
    long long i = (long long)blockIdx.x * blockDim.x + threadIdx.x;
    if (i >= NELEM4) return;
    const long long user4 = (long long)USER_NUM * D / 4;
    float4 v = (i < user4) ? user_emb[i] : item_emb[i - user4];
    out[i] = v;
    __half h0 = __float2half_rn(v.x), h1 = __float2half_rn(v.y);
    __half h2 = __float2half_rn(v.z), h3 = __float2half_rn(v.w);
    cur[i] = make_ushort4(*(unsigned short*)&h0, *(unsigned short*)&h1,
                          *(unsigned short*)&h2, *(unsigned short*)&h3);
}

// ---------------------------------------------------------------- pass A: bin
// Per block: LDS histogram over its 8192 edges -> one global atomicAdd per
// touched bin (range reservation) -> scatter packed edges into per-bin
// segments. Segment writes per (block,bin) are contiguous, so cache lines
// fill before eviction.
__global__ __launch_bounds__(256) void binA_kernel(
        const int*   __restrict__ src,
        const int*   __restrict__ dst,
        const float* __restrict__ w,
        int*            __restrict__ bin_cnt,
        unsigned*       __restrict__ segA,
        unsigned short* __restrict__ segB) {
    __shared__ int off[NBINS];
    const int tid = threadIdx.x;
    const long long e0 = (long long)blockIdx.x * EPB;
    const int nE = (int)((N_EDGES - e0) < EPB ? (N_EDGES - e0) : EPB);

    for (int i = tid; i < NBINS; i += 256) off[i] = 0;
    __syncthreads();

    // phase 1: histogram (LDS atomics)
    for (int k = tid; k < nE; k += 256) {
        int d = dst[e0 + k];
        atomicAdd(&off[d >> BIN_SHIFT], 1);
    }
    __syncthreads();

    // phase 2: reserve contiguous global ranges (1 global atomic per bin)
    for (int i = tid; i < NBINS; i += 256) {
        int c = off[i];
        off[i] = c ? atomicAdd(&bin_cnt[i], c) : 0;
    }
    __syncthreads();

    // phase 3: scatter into per-bin segments
    for (int k = tid; k < nE; k += 256) {
        int   s  = src[e0 + k];
        int   d  = dst[e0 + k];
        float ww = w[e0 + k];
        unsigned q = (unsigned)(ww * 8191.0f + 0.5f);
        int bin = d >> BIN_SHIFT;
        int pos = atomicAdd(&off[bin], 1);
        if (pos < BIN_CAP) {
            long long idx = (long long)bin * BIN_CAP + pos;
            segA[idx] = (q << 19) | (unsigned)s;
            segB[idx] = (unsigned short)(d & (BIN_NODES - 1));
        }
    }
}

// ---------------------------------------------------------------- pass B: fill
// One block per bin. Slot allocation via LDS counters (no global atomics);
// scattered slot stores confined to the bin's 512*CAP*4 = 192 KB region,
// which stays resident in the local XCD L2 -> lines written back once, full.
__global__ __launch_bounds__(512) void binB_kernel(
        const int*            __restrict__ bin_cnt,
        const unsigned*       __restrict__ segA,
        const unsigned short* __restrict__ segB,
        int*      __restrict__ deg,
        unsigned* __restrict__ slots) {
    __shared__ int dl[BIN_NODES];
    const int bin = blockIdx.x;
    const int tid = threadIdx.x;
    dl[tid] = 0;
    __syncthreads();

    int n = bin_cnt[bin];
    if (n > BIN_CAP) n = BIN_CAP;
    const long long base  = (long long)bin * BIN_CAP;
    const int       node0 = bin * BIN_NODES;

    int i = tid;
    for (; i + 1536 < n; i += 2048) {   // 4-unroll for MLP (only ~2.3 blk/CU)
        unsigned v0 = segA[base + i];
        unsigned v1 = segA[base + i + 512];
        unsigned v2 = segA[base + i + 1024];
        unsigned v3 = segA[base + i + 1536];
        int l0 = segB[base + i];
        int l1 = segB[base + i + 512];
        int l2 = segB[base + i + 1024];
        int l3 = segB[base + i + 1536];
        int p0 = atomicAdd(&dl[l0], 1);
        int p1 = atomicAdd(&dl[l1], 1);
        int p2 = atomicAdd(&dl[l2], 1);
        int p3 = atomicAdd(&dl[l3], 1);
        if (p0 < CAP) slots[(long long)(node0 + l0) * CAP + p0] = v0;
        if (p1 < CAP) slots[(long long)(node0 + l1) * CAP + p1] = v1;
        if (p2 < CAP) slots[(long long)(node0 + l2) * CAP + p2] = v2;
        if (p3 < CAP) slots[(long long)(node0 + l3) * CAP + p3] = v3;
    }
    for (; i < n; i += 512) {
        unsigned v = segA[base + i];
        int      l = segB[base + i];
        int      p = atomicAdd(&dl[l], 1);
        if (p < CAP) slots[(long long)(node0 + l) * CAP + p] = v;
    }
    __syncthreads();

    int node = node0 + tid;
    if (tid < BIN_NODES && node < N_NODES) deg[node] = dl[tid];
}

// ---------------------------------------------------------------- gather SpMM
// TWO nodes per wave: half = lane>>5 picks the node, col = lane&31 covers the
// 64-dim row as half2 (4 B/lane x 32 lanes = 128-B row). One gather
// instruction fetches both halves' (independent) edge rows -> 2x memory-level
// parallelism per instruction vs one-node-per-wave. Divergent per-half loop
// bounds are handled by exec masking. fp32 accumulate, fused out epilogue.
template <bool LAST>
__global__ void spmm_gather(const int*      __restrict__ deg,
                            const unsigned* __restrict__ slots,
                            const __half2*  __restrict__ cur,   // rows of 32 half2
                            __half2*        __restrict__ next,
                            float2*         __restrict__ out) {
    long long t = (long long)blockIdx.x * blockDim.x + threadIdx.x;
    int wave = (int)(t >> 6);
    int lane = (int)(t & 63);
    int half = lane >> 5;
    int col  = lane & 31;
    int node = wave * 2 + half;
    if (node >= N_NODES) return;
    int n = deg[node];
    if (n > CAP) n = CAP;
    const unsigned* sl = slots + (long long)node * CAP;
    float accx = 0.f, accy = 0.f;
    int i = 0;
    for (; i + 3 < n; i += 4) {        // 4-unroll x 2 halves = 8 rows in flight
        unsigned e0 = sl[i + 0];
        unsigned e1 = sl[i + 1];
        unsigned e2 = sl[i + 2];
        unsigned e3 = sl[i + 3];
        __half2 x0 = cur[(long long)(e0 & SRC_MASK) * 32 + col];
        __half2 x1 = cur[(long long)(e1 & SRC_MASK) * 32 + col];
        __half2 x2 = cur[(long long)(e2 & SRC_MASK) * 32 + col];
        __half2 x3 = cur[(long long)(e3 & SRC_MASK) * 32 + col];
        float w0 = (float)(e0 >> 19) * W_SCALE;
        float w1 = (float)(e1 >> 19) * W_SCALE;
        float w2 = (float)(e2 >> 19) * W_SCALE;
        float w3 = (float)(e3 >> 19) * W_SCALE;
        float2 f0 = __half22float2(x0);
        float2 f1 = __half22float2(x1);
        float2 f2 = __half22float2(x2);
        float2 f3 = __half22float2(x3);
        accx = fmaf(w0, f0.x, accx); accy = fmaf(w0, f0.y, accy);
        accx = fmaf(w1, f1.x, accx); accy = fmaf(w1, f1.y, accy);
        accx = fmaf(w2, f2.x, accx); accy = fmaf(w2, f2.y, accy);
        accx = fmaf(w3, f3.x, accx); accy = fmaf(w3, f3.y, accy);
    }
    for (; i < n; ++i) {
        unsigned e0 = sl[i];
        __half2 x0 = cur[(long long)(e0 & SRC_MASK) * 32 + col];
        float w0 = (float)(e0 >> 19) * W_SCALE;
        float2 f0 = __half22float2(x0);
        accx = fmaf(w0, f0.x, accx); accy = fmaf(w0, f0.y, accy);
    }
    long long oi = (long long)node * 32 + col;
    if (!LAST) {
        __half2 h; h.x = __float2half_rn(accx); h.y = __float2half_rn(accy);
        next[oi] = h;
    }
    float2 o = out[oi];
    o.x += accx; o.y += accy;
    if (LAST) { o.x *= 0.25f; o.y *= 0.25f; }
    out[oi] = o;
}

// ---------------------------------------------------------------- launch
extern "C" void kernel_launch(void* const* d_in, const int* in_sizes, int n_in,
                              void* d_out, int out_size, void* d_ws, size_t ws_size,
                              hipStream_t stream) {
    const float* user_emb = (const float*)d_in[0];
    const float* item_emb = (const float*)d_in[1];
    const float* ew       = (const float*)d_in[2];
    const int*   es       = (const int*)d_in[3];
    const int*   ed       = (const int*)d_in[4];
    float* out = (float*)d_out;

    // ws layout: cur(fp16) | next(fp16) | deg(int xN) | slots(u32 x N*CAP)
    //          | bin_cnt(int x NBINS)
    // = 38.4 + 38.4 + 1.2 + 115.2 + ~0.002 MB ~= 193.2 MB.
    // seg arrays (40.8 + 20.4 MB) OVERLAP buf0/buf1: they are dead after
    // binB_kernel, and init_kernel (which writes buf0) launches after it on
    // the same stream. slots byte offset 78,000,000 is 64-aligned -> 384-B
    // bucket rows are line-aligned.
    __half* buf0 = (__half*)d_ws;
    __half* buf1 = buf0 + NELEM;
    int*      deg     = (int*)(buf1 + NELEM);
    unsigned* slots   = (unsigned*)(deg + N_NODES);
    int*      bin_cnt = (int*)(slots + (long long)N_NODES * CAP);
    unsigned*       segA = (unsigned*)d_ws;                       // 40,804,352 B
    unsigned short* segB = (unsigned short*)(segA + (long long)NBINS * BIN_CAP);
    // segB end = 61,206,528 B < 76,800,000 (deg offset): no overlap with deg.

    const int B = 256;
    const long long node_waves  = (N_NODES + 1) / 2;                       // 150000
    const long long node_blocks = (node_waves * 64 + B - 1) / B;           // 37500
    const long long init_blocks = (NELEM4 + B - 1) / B;

    // ---- binned bucket build ----
    hipMemsetAsync(bin_cnt, 0, (size_t)NBINS * 4, stream);
    binA_kernel<<<dim3((unsigned)NBLK_A), dim3(256), 0, stream>>>(
        es, ed, ew, bin_cnt, segA, segB);
    binB_kernel<<<dim3((unsigned)NBINS), dim3(512), 0, stream>>>(
        bin_cnt, segA, segB, deg, slots);

    // out = all_emb (fp32); cur = fp16(all_emb). After binB (seg overlap).
    init_kernel<<<dim3((unsigned)init_blocks), dim3(B), 0, stream>>>(
        (const float4*)user_emb, (const float4*)item_emb,
        (float4*)out, (ushort4*)buf0);

    // ---- 3 gather layers, epilogue fused ----
    spmm_gather<false><<<dim3((unsigned)node_blocks), dim3(B), 0, stream>>>(
        deg, slots, (const __half2*)buf0, (__half2*)buf1, (float2*)out);
    spmm_gather<false><<<dim3((unsigned)node_blocks), dim3(B), 0, stream>>>(
        deg, slots, (const __half2*)buf1, (__half2*)buf0, (float2*)out);
    spmm_gather<true><<<dim3((unsigned)node_blocks), dim3(B), 0, stream>>>(
        deg, slots, (const __half2*)buf0, (__half2*)buf1, (float2*)out);
}

// Round 2
// 967.097 us; speedup vs baseline: 1.3794x; 1.3752x over previous
//
#include <hip/hip_runtime.h>
#include <hip/hip_fp16.h>

#define USER_NUM 200000
#define ITEM_NUM 100000
#define N_NODES  300000   // USER_NUM + ITEM_NUM
#define N_EDGES  9600000
#define D        64
#define NELEM    ((long long)N_NODES * D)       // 19,200,000
#define NELEM4   (NELEM / 4)                    // 4,800,000

// Fixed-capacity bucket per node. deg ~ Poisson(32), max for this dataset
// ~60; CAP=96 leaves huge margin (clamp guard below makes OOB impossible).
#define CAP 96

// Slot entry packing: [31:19] = 13-bit weight q (w = q/8191), [18:0] = src id.
#define SRC_MASK 0x7FFFFu
#define W_SCALE  (1.0f / 8191.0f)

// ---- binned bucket-build geometry (LDS-staged, full-line writes) ----
// Round-1 lesson: any scheme whose scatter goes through global cache lines
// thrashes — in-flight partial lines = resident_threads x edges/thread x
// entry_bytes >> per-XCD L2 (9+ MB vs 4 MB) regardless of EPB/NBINS, giving
// the measured 9.5x WRITE amplification (545 MB for 57.6 MB of data).
// Fix: pass A is a block-local counting sort. Edges are scattered into an
// LDS staging buffer (no line semantics), then streamed out as one
// contiguous 56 KB block-own region with full-line u64 stores. Per-
// (block,bin) fragment locations go to a compact blk_info aux array.
// Pass B walks one bin's fragments, deg counters in LDS, slot scatter
// confined to the bin's 384 KB region (L2-local).
#define BIN_NODES 1024
#define BIN_SHIFT 10
#define NBINS     ((N_NODES + BIN_NODES - 1) / BIN_NODES)   // 293
#define EPB       7168    // edges per block: stage 56 KB + 2x1.2 KB < 64 KB LDS
#define NBLK_A    ((N_EDGES + EPB - 1) / EPB)               // 1340
#define BPG       ((NBLK_A + 15) / 16)                      // 84 blks per group

// ---------------------------------------------------------------- init
// out = all_emb (fp32), cur = fp16(all_emb). 4 elements/thread.
__global__ void init_kernel(const float4* __restrict__ user_emb,
                            const float4* __restrict__ item_emb,
                            float4* __restrict__ out,
                            ushort4* __restrict__ cur) {
    long long i = (long long)blockIdx.x * blockDim.x + threadIdx.x;
    if (i >= NELEM4) return;
    const long long user4 = (long long)USER_NUM * D / 4;
    float4 v = (i < user4) ? user_emb[i] : item_emb[i - user4];
    out[i] = v;
    __half h0 = __float2half_rn(v.x), h1 = __float2half_rn(v.y);
    __half h2 = __float2half_rn(v.z), h3 = __float2half_rn(v.w);
    cur[i] = make_ushort4(*(unsigned short*)&h0, *(unsigned short*)&h1,
                          *(unsigned short*)&h2, *(unsigned short*)&h3);
}

// ---------------------------------------------------------------- pass A
// Block-local counting sort of EPB edges by bin, staged in LDS.
// Entry: u64 = (local_node << 32) | (q << 19) | src.
// Output: seg[blk*EPB ..] sorted-by-bin (full-line streaming stores), plus
// blk_info[bin][blk] = (start_in_block << 16) | count (both < 7168, fit u16).
// No global atomics, no capacity slack: positions are exact.
__global__ __launch_bounds__(512) void binA_kernel(
        const int*   __restrict__ src,
        const int*   __restrict__ dst,
        const float* __restrict__ w,
        unsigned long long* __restrict__ seg,
        unsigned*           __restrict__ blk_info) {
    __shared__ unsigned long long stage[EPB];   // 57,344 B
    __shared__ int hist[NBINS];                 //  1,172 B
    __shared__ int off[NBINS];                  //  1,172 B
    const int tid = threadIdx.x;
    const long long e0 = (long long)blockIdx.x * EPB;
    long long rem = (long long)N_EDGES - e0;
    const int nE = (int)(rem < EPB ? rem : EPB);   // always a multiple of 4

    for (int i = tid; i < NBINS; i += 512) hist[i] = 0;
    __syncthreads();

    // phase 1: histogram over bins (LDS atomics), int4 loads
    for (int k = tid * 4; k < nE; k += 512 * 4) {
        int4 d4 = *(const int4*)(dst + e0 + k);
        atomicAdd(&hist[d4.x >> BIN_SHIFT], 1);
        atomicAdd(&hist[d4.y >> BIN_SHIFT], 1);
        atomicAdd(&hist[d4.z >> BIN_SHIFT], 1);
        atomicAdd(&hist[d4.w >> BIN_SHIFT], 1);
    }
    __syncthreads();

    // phase 2: Hillis-Steele inclusive scan -> exclusive offsets; emit info
    if (tid < NBINS) off[tid] = hist[tid];
    __syncthreads();
    for (int s = 1; s < NBINS; s <<= 1) {
        int v = 0;
        if (tid < NBINS && tid >= s) v = off[tid - s];
        __syncthreads();
        if (tid < NBINS && tid >= s) off[tid] += v;
        __syncthreads();
    }
    if (tid < NBINS) {
        int excl = off[tid] - hist[tid];
        off[tid] = excl;
        blk_info[(long long)tid * NBLK_A + blockIdx.x] =
            ((unsigned)excl << 16) | (unsigned)hist[tid];
    }
    __syncthreads();

    // phase 3: scatter into LDS stage (8-B LDS writes: no line thrash)
    for (int k = tid * 4; k < nE; k += 512 * 4) {
        int4   s4 = *(const int4*)(src + e0 + k);
        int4   d4 = *(const int4*)(dst + e0 + k);
        float4 w4 = *(const float4*)(w + e0 + k);
#define DO_EDGE(S, DD, W) { \
        unsigned q = (unsigned)((W) * 8191.0f + 0.5f); \
        int bin = (DD) >> BIN_SHIFT; \
        int pos = atomicAdd(&off[bin], 1); \
        stage[pos] = ((unsigned long long)(unsigned)((DD) & (BIN_NODES - 1)) << 32) \
                   | ((q << 19) | (unsigned)(S)); }
        DO_EDGE(s4.x, d4.x, w4.x)
        DO_EDGE(s4.y, d4.y, w4.y)
        DO_EDGE(s4.z, d4.z, w4.z)
        DO_EDGE(s4.w, d4.w, w4.w)
#undef DO_EDGE
    }
    __syncthreads();

    // phase 4: stream sorted block region to global (full-line u64 stores)
    for (int k = tid; k < nE; k += 512)
        seg[e0 + k] = stage[k];
}

// ---------------------------------------------------------------- pass B
// One block per bin. Walks the bin's 1340 fragments (mean 24.5 edges each:
// 32-lane groups, 16 per block). Slot allocation via LDS counters; scattered
// slot stores confined to the bin's 1024*CAP*4 = 384 KB region.
__global__ __launch_bounds__(512) void binB_kernel(
        const unsigned*           __restrict__ blk_info,
        const unsigned long long* __restrict__ seg,
        int*      __restrict__ deg,
        unsigned* __restrict__ slots) {
    __shared__ int dl[BIN_NODES];        // 4 KB
    __shared__ unsigned info[NBLK_A];    // 5.4 KB
    const int bin = blockIdx.x;
    const int tid = threadIdx.x;
    dl[tid] = 0; dl[tid + 512] = 0;
    for (int i = tid; i < NBLK_A; i += 512)
        info[i] = blk_info[(long long)bin * NBLK_A + i];
    __syncthreads();

    const int node0 = bin << BIN_SHIFT;
    const int grp = tid >> 5;            // 16 groups of 32 lanes
    const int gl  = tid & 31;
    int b1 = grp * BPG + BPG;
    if (b1 > NBLK_A) b1 = NBLK_A;
    for (int blk = grp * BPG; blk < b1; ++blk) {
        unsigned inf = info[blk];
        int cnt = (int)(inf & 0xFFFFu);
        long long base = (long long)blk * EPB + (inf >> 16);
        for (int j = gl; j < cnt; j += 32) {
            unsigned long long v = seg[base + j];
            int l = (int)(v >> 32);
            int p = atomicAdd(&dl[l], 1);
            if (p < CAP) slots[(long long)(node0 + l) * CAP + p] = (unsigned)v;
        }
    }
    __syncthreads();

    int node = node0 + tid;
    if (node < N_NODES) deg[node] = dl[tid];
    node += 512;
    if (tid + 512 < BIN_NODES && node < N_NODES) deg[node] = dl[tid + 512];
}

// ---------------------------------------------------------------- gather SpMM
// TWO nodes per wave: half = lane>>5 picks the node, col = lane&31 covers the
// 64-dim row as half2 (4 B/lane x 32 lanes = 128-B row). One gather
// instruction fetches both halves' (independent) edge rows -> 2x memory-level
// parallelism per instruction vs one-node-per-wave. Divergent per-half loop
// bounds are handled by exec masking. fp32 accumulate, fused out epilogue.
template <bool LAST>
__global__ void spmm_gather(const int*      __restrict__ deg,
                            const unsigned* __restrict__ slots,
                            const __half2*  __restrict__ cur,   // rows of 32 half2
                            __half2*        __restrict__ next,
                            float2*         __restrict__ out) {
    long long t = (long long)blockIdx.x * blockDim.x + threadIdx.x;
    int wave = (int)(t >> 6);
    int lane = (int)(t & 63);
    int half = lane >> 5;
    int col  = lane & 31;
    int node = wave * 2 + half;
    if (node >= N_NODES) return;
    int n = deg[node];
    if (n > CAP) n = CAP;
    const unsigned* sl = slots + (long long)node * CAP;
    float accx = 0.f, accy = 0.f;
    int i = 0;
    for (; i + 3 < n; i += 4) {        // 4-unroll x 2 halves = 8 rows in flight
        unsigned e0 = sl[i + 0];
        unsigned e1 = sl[i + 1];
        unsigned e2 = sl[i + 2];
        unsigned e3 = sl[i + 3];
        __half2 x0 = cur[(long long)(e0 & SRC_MASK) * 32 + col];
        __half2 x1 = cur[(long long)(e1 & SRC_MASK) * 32 + col];
        __half2 x2 = cur[(long long)(e2 & SRC_MASK) * 32 + col];
        __half2 x3 = cur[(long long)(e3 & SRC_MASK) * 32 + col];
        float w0 = (float)(e0 >> 19) * W_SCALE;
        float w1 = (float)(e1 >> 19) * W_SCALE;
        float w2 = (float)(e2 >> 19) * W_SCALE;
        float w3 = (float)(e3 >> 19) * W_SCALE;
        float2 f0 = __half22float2(x0);
        float2 f1 = __half22float2(x1);
        float2 f2 = __half22float2(x2);
        float2 f3 = __half22float2(x3);
        accx = fmaf(w0, f0.x, accx); accy = fmaf(w0, f0.y, accy);
        accx = fmaf(w1, f1.x, accx); accy = fmaf(w1, f1.y, accy);
        accx = fmaf(w2, f2.x, accx); accy = fmaf(w2, f2.y, accy);
        accx = fmaf(w3, f3.x, accx); accy = fmaf(w3, f3.y, accy);
    }
    for (; i < n; ++i) {
        unsigned e0 = sl[i];
        __half2 x0 = cur[(long long)(e0 & SRC_MASK) * 32 + col];
        float w0 = (float)(e0 >> 19) * W_SCALE;
        float2 f0 = __half22float2(x0);
        accx = fmaf(w0, f0.x, accx); accy = fmaf(w0, f0.y, accy);
    }
    long long oi = (long long)node * 32 + col;
    if (!LAST) {
        __half2 h; h.x = __float2half_rn(accx); h.y = __float2half_rn(accy);
        next[oi] = h;
    }
    float2 o = out[oi];
    o.x += accx; o.y += accy;
    if (LAST) { o.x *= 0.25f; o.y *= 0.25f; }
    out[oi] = o;
}

// ---------------------------------------------------------------- launch
extern "C" void kernel_launch(void* const* d_in, const int* in_sizes, int n_in,
                              void* d_out, int out_size, void* d_ws, size_t ws_size,
                              hipStream_t stream) {
    const float* user_emb = (const float*)d_in[0];
    const float* item_emb = (const float*)d_in[1];
    const float* ew       = (const float*)d_in[2];
    const int*   es       = (const int*)d_in[3];
    const int*   ed       = (const int*)d_in[4];
    float* out = (float*)d_out;

    // ws layout:
    //   slots   u32 x N_NODES*CAP        [0          .. 115,200,000)
    //   deg     int x N_NODES            [115.2M     .. 116,400,000)
    //   buf0    fp16 x NELEM             [116.4M     .. 154,800,000)
    //   buf1    fp16 x NELEM             [154.8M     .. 193,200,000)
    //   seg     u64 x NBLK_A*EPB  (overlays buf0/buf1; dead before init)
    //                                    [116.4M     .. 193,240,960)
    //   blk_info u32 x NBINS*NBLK_A      [193,240,960.. 194,811,440)
    // max touched ~194.8 MB (prior sessions verified 235 MB fits).
    // seg/blk_info are written by binA, consumed by binB, and only then does
    // init_kernel overwrite buf0 — stream order makes the overlay safe.
    unsigned* slots = (unsigned*)d_ws;
    int*      deg   = (int*)((char*)d_ws + (long long)N_NODES * CAP * 4);
    __half*   buf0  = (__half*)(deg + N_NODES);
    __half*   buf1  = buf0 + NELEM;
    unsigned long long* seg = (unsigned long long*)buf0;
    unsigned* blk_info = (unsigned*)(seg + (long long)NBLK_A * EPB);

    const int B = 256;
    const long long node_waves  = (N_NODES + 1) / 2;                       // 150000
    const long long node_blocks = (node_waves * 64 + B - 1) / B;           // 37500
    const long long init_blocks = (NELEM4 + B - 1) / B;

    // ---- LDS-staged binned bucket build (no global atomics, no memset) ----
    binA_kernel<<<dim3((unsigned)NBLK_A), dim3(512), 0, stream>>>(
        es, ed, ew, seg, blk_info);
    binB_kernel<<<dim3((unsigned)NBINS), dim3(512), 0, stream>>>(
        blk_info, seg, deg, slots);

    // out = all_emb (fp32); cur = fp16(all_emb). After binB (seg overlay).
    init_kernel<<<dim3((unsigned)init_blocks), dim3(B), 0, stream>>>(
        (const float4*)user_emb, (const float4*)item_emb,
        (float4*)out, (ushort4*)buf0);

    // ---- 3 gather layers, epilogue fused ----
    spmm_gather<false><<<dim3((unsigned)node_blocks), dim3(B), 0, stream>>>(
        deg, slots, (const __half2*)buf0, (__half2*)buf1, (float2*)out);
    spmm_gather<false><<<dim3((unsigned)node_blocks), dim3(B), 0, stream>>>(
        deg, slots, (const __half2*)buf1, (__half2*)buf0, (float2*)out);
    spmm_gather<true><<<dim3((unsigned)node_blocks), dim3(B), 0, stream>>>(
        deg, slots, (const __half2*)buf0, (__half2*)buf1, (float2*)out);
}

// Round 3
// 866.538 us; speedup vs baseline: 1.5395x; 1.1160x over previous
//
#include <hip/hip_runtime.h>
#include <hip/hip_fp16.h>

#define USER_NUM 200000
#define ITEM_NUM 100000
#define N_NODES  300000   // USER_NUM + ITEM_NUM
#define N_EDGES  9600000
#define D        64
#define NELEM    ((long long)N_NODES * D)       // 19,200,000
#define NELEM4   (NELEM / 4)                    // 4,800,000

// Fixed-capacity bucket per node. deg ~ Poisson(32), max for this dataset
// ~60; CAP=96 leaves huge margin (clamp guard below makes OOB impossible).
#define CAP 96

// Slot entry packing: [31:19] = 13-bit weight q (w = q/8191), [18:0] = src id.
#define SRC_MASK 0x7FFFFu
#define W_SCALE  (1.0f / 8191.0f)

// ---- binned bucket-build geometry (LDS-staged, full-line writes) ----
// Round-1 lesson: any scheme whose scatter goes through global cache lines
// thrashes — in-flight partial lines >> per-XCD L2 regardless of tuning
// (measured 9.5x WRITE amplification). Pass A = block-local counting sort
// staged in LDS, streamed out as full lines. Pass B = per-bin fill, deg
// counters in LDS, slot scatter confined to the bin's 384 KB L2-local region.
#define BIN_NODES 1024
#define BIN_SHIFT 10
#define NBINS     ((N_NODES + BIN_NODES - 1) / BIN_NODES)   // 293
#define EPB       7168    // edges per block: stage 56 KB + 2x1.2 KB < 64 KB LDS
#define NBLK_A    ((N_EDGES + EPB - 1) / EPB)               // 1340
#define BPG       ((NBLK_A + 15) / 16)                      // 84 blks per group

// ---------------------------------------------------------------- init
// cur = fp16(all_emb). out is no longer touched here: the final layer
// reconstructs the layer-sum from the per-layer fp16 buffers (saves a 77 MB
// fp32 out-write here and 154 MB of out RMW in each of layers 1-2).
__global__ void init_kernel(const float4* __restrict__ user_emb,
                            const float4* __restrict__ item_emb,
                            ushort4* __restrict__ cur) {
    long long i = (long long)blockIdx.x * blockDim.x + threadIdx.x;
    if (i >= NELEM4) return;
    const long long user4 = (long long)USER_NUM * D / 4;
    float4 v = (i < user4) ? user_emb[i] : item_emb[i - user4];
    __half h0 = __float2half_rn(v.x), h1 = __float2half_rn(v.y);
    __half h2 = __float2half_rn(v.z), h3 = __float2half_rn(v.w);
    cur[i] = make_ushort4(*(unsigned short*)&h0, *(unsigned short*)&h1,
                          *(unsigned short*)&h2, *(unsigned short*)&h3);
}

// ---------------------------------------------------------------- pass A
// Block-local counting sort of EPB edges by bin, staged in LDS.
// Entry: u64 = (local_node << 32) | (q << 19) | src.
// Output: seg[blk*EPB ..] sorted-by-bin (full-line streaming stores), plus
// blk_info[bin][blk] = (start_in_block << 16) | count (both < 7168, fit u16).
__global__ __launch_bounds__(512) void binA_kernel(
        const int*   __restrict__ src,
        const int*   __restrict__ dst,
        const float* __restrict__ w,
        unsigned long long* __restrict__ seg,
        unsigned*           __restrict__ blk_info) {
    __shared__ unsigned long long stage[EPB];   // 57,344 B
    __shared__ int hist[NBINS];                 //  1,172 B
    __shared__ int off[NBINS];                  //  1,172 B
    const int tid = threadIdx.x;
    const long long e0 = (long long)blockIdx.x * EPB;
    long long rem = (long long)N_EDGES - e0;
    const int nE = (int)(rem < EPB ? rem : EPB);   // always a multiple of 4

    for (int i = tid; i < NBINS; i += 512) hist[i] = 0;
    __syncthreads();

    // phase 1: histogram over bins (LDS atomics), int4 loads
    for (int k = tid * 4; k < nE; k += 512 * 4) {
        int4 d4 = *(const int4*)(dst + e0 + k);
        atomicAdd(&hist[d4.x >> BIN_SHIFT], 1);
        atomicAdd(&hist[d4.y >> BIN_SHIFT], 1);
        atomicAdd(&hist[d4.z >> BIN_SHIFT], 1);
        atomicAdd(&hist[d4.w >> BIN_SHIFT], 1);
    }
    __syncthreads();

    // phase 2: Hillis-Steele inclusive scan -> exclusive offsets; emit info
    if (tid < NBINS) off[tid] = hist[tid];
    __syncthreads();
    for (int s = 1; s < NBINS; s <<= 1) {
        int v = 0;
        if (tid < NBINS && tid >= s) v = off[tid - s];
        __syncthreads();
        if (tid < NBINS && tid >= s) off[tid] += v;
        __syncthreads();
    }
    if (tid < NBINS) {
        int excl = off[tid] - hist[tid];
        off[tid] = excl;
        blk_info[(long long)tid * NBLK_A + blockIdx.x] =
            ((unsigned)excl << 16) | (unsigned)hist[tid];
    }
    __syncthreads();

    // phase 3: scatter into LDS stage (8-B LDS writes: no line thrash)
    for (int k = tid * 4; k < nE; k += 512 * 4) {
        int4   s4 = *(const int4*)(src + e0 + k);
        int4   d4 = *(const int4*)(dst + e0 + k);
        float4 w4 = *(const float4*)(w + e0 + k);
#define DO_EDGE(S, DD, W) { \
        unsigned q = (unsigned)((W) * 8191.0f + 0.5f); \
        int bin = (DD) >> BIN_SHIFT; \
        int pos = atomicAdd(&off[bin], 1); \
        stage[pos] = ((unsigned long long)(unsigned)((DD) & (BIN_NODES - 1)) << 32) \
                   | ((q << 19) | (unsigned)(S)); }
        DO_EDGE(s4.x, d4.x, w4.x)
        DO_EDGE(s4.y, d4.y, w4.y)
        DO_EDGE(s4.z, d4.z, w4.z)
        DO_EDGE(s4.w, d4.w, w4.w)
#undef DO_EDGE
    }
    __syncthreads();

    // phase 4: stream sorted block region to global (full-line u64 stores)
    for (int k = tid; k < nE; k += 512)
        seg[e0 + k] = stage[k];
}

// ---------------------------------------------------------------- pass B
// One block per bin. Walks the bin's 1340 fragments (mean 24.5 edges each:
// 32-lane groups, 16 per block). Slot allocation via LDS counters; scattered
// slot stores confined to the bin's 1024*CAP*4 = 384 KB region.
__global__ __launch_bounds__(512) void binB_kernel(
        const unsigned*           __restrict__ blk_info,
        const unsigned long long* __restrict__ seg,
        int*      __restrict__ deg,
        unsigned* __restrict__ slots) {
    __shared__ int dl[BIN_NODES];        // 4 KB
    __shared__ unsigned info[NBLK_A];    // 5.4 KB
    const int bin = blockIdx.x;
    const int tid = threadIdx.x;
    dl[tid] = 0; dl[tid + 512] = 0;
    for (int i = tid; i < NBLK_A; i += 512)
        info[i] = blk_info[(long long)bin * NBLK_A + i];
    __syncthreads();

    const int node0 = bin << BIN_SHIFT;
    const int grp = tid >> 5;            // 16 groups of 32 lanes
    const int gl  = tid & 31;
    int b1 = grp * BPG + BPG;
    if (b1 > NBLK_A) b1 = NBLK_A;
    for (int blk = grp * BPG; blk < b1; ++blk) {
        unsigned inf = info[blk];
        int cnt = (int)(inf & 0xFFFFu);
        long long base = (long long)blk * EPB + (inf >> 16);
        for (int j = gl; j < cnt; j += 32) {
            unsigned long long v = seg[base + j];
            int l = (int)(v >> 32);
            int p = atomicAdd(&dl[l], 1);
            if (p < CAP) slots[(long long)(node0 + l) * CAP + p] = (unsigned)v;
        }
    }
    __syncthreads();

    int node = node0 + tid;
    if (node < N_NODES) deg[node] = dl[tid];
    node += 512;
    if (tid + 512 < BIN_NODES && node < N_NODES) deg[node] = dl[tid + 512];
}

// ---------------------------------------------------------------- gather SpMM
// TWO nodes per wave: half = lane>>5 picks the node, col = lane&31 covers the
// 64-dim row as half2 (4 B/lane x 32 lanes = 128-B row). 8-deep unroll keeps
// 16 cache lines in flight per wave. fp32 accumulate.
// !LAST: write fp16 layer output only (no out traffic at all).
// LAST:  fuse the mean: out = (x0 + x1 + x2 + acc) * 0.25 where x0,x1 come
//        from the per-layer fp16 buffers (coalesced own-row reads) and x2 is
//        cur's own row. Replaces per-layer fp32 out RMW (308 MB) with 77 MB
//        of fp16 sequential reads in the last layer.
template <bool LAST>
__global__ void spmm_gather(const int*      __restrict__ deg,
                            const unsigned* __restrict__ slots,
                            const __half2*  __restrict__ cur,   // rows of 32 half2
                            __half2*        __restrict__ next,
                            const __half2*  __restrict__ x0b,
                            const __half2*  __restrict__ x1b,
                            float2*         __restrict__ out) {
    long long t = (long long)blockIdx.x * blockDim.x + threadIdx.x;
    int wave = (int)(t >> 6);
    int lane = (int)(t & 63);
    int half = lane >> 5;
    int col  = lane & 31;
    int node = wave * 2 + half;
    if (node >= N_NODES) return;
    int n = deg[node];
    if (n > CAP) n = CAP;
    const unsigned* sl = slots + (long long)node * CAP;
    float accx = 0.f, accy = 0.f;
    float bccx = 0.f, bccy = 0.f;
    int i = 0;
    for (; i + 7 < n; i += 8) {        // 8-unroll x 2 halves = 16 rows in flight
        uint4 ea = *(const uint4*)(sl + i);
        uint4 eb = *(const uint4*)(sl + i + 4);
        __half2 x0 = cur[(long long)(ea.x & SRC_MASK) * 32 + col];
        __half2 x1 = cur[(long long)(ea.y & SRC_MASK) * 32 + col];
        __half2 x2 = cur[(long long)(ea.z & SRC_MASK) * 32 + col];
        __half2 x3 = cur[(long long)(ea.w & SRC_MASK) * 32 + col];
        __half2 x4 = cur[(long long)(eb.x & SRC_MASK) * 32 + col];
        __half2 x5 = cur[(long long)(eb.y & SRC_MASK) * 32 + col];
        __half2 x6 = cur[(long long)(eb.z & SRC_MASK) * 32 + col];
        __half2 x7 = cur[(long long)(eb.w & SRC_MASK) * 32 + col];
        float w0 = (float)(ea.x >> 19) * W_SCALE;
        float w1 = (float)(ea.y >> 19) * W_SCALE;
        float w2 = (float)(ea.z >> 19) * W_SCALE;
        float w3 = (float)(ea.w >> 19) * W_SCALE;
        float w4 = (float)(eb.x >> 19) * W_SCALE;
        float w5 = (float)(eb.y >> 19) * W_SCALE;
        float w6 = (float)(eb.z >> 19) * W_SCALE;
        float w7 = (float)(eb.w >> 19) * W_SCALE;
        float2 f0 = __half22float2(x0);
        float2 f1 = __half22float2(x1);
        float2 f2 = __half22float2(x2);
        float2 f3 = __half22float2(x3);
        float2 f4 = __half22float2(x4);
        float2 f5 = __half22float2(x5);
        float2 f6 = __half22float2(x6);
        float2 f7 = __half22float2(x7);
        accx = fmaf(w0, f0.x, accx); accy = fmaf(w0, f0.y, accy);
        bccx = fmaf(w1, f1.x, bccx); bccy = fmaf(w1, f1.y, bccy);
        accx = fmaf(w2, f2.x, accx); accy = fmaf(w2, f2.y, accy);
        bccx = fmaf(w3, f3.x, bccx); bccy = fmaf(w3, f3.y, bccy);
        accx = fmaf(w4, f4.x, accx); accy = fmaf(w4, f4.y, accy);
        bccx = fmaf(w5, f5.x, bccx); bccy = fmaf(w5, f5.y, bccy);
        accx = fmaf(w6, f6.x, accx); accy = fmaf(w6, f6.y, accy);
        bccx = fmaf(w7, f7.x, bccx); bccy = fmaf(w7, f7.y, bccy);
    }
    for (; i + 3 < n; i += 4) {
        uint4 ea = *(const uint4*)(sl + i);
        __half2 x0 = cur[(long long)(ea.x & SRC_MASK) * 32 + col];
        __half2 x1 = cur[(long long)(ea.y & SRC_MASK) * 32 + col];
        __half2 x2 = cur[(long long)(ea.z & SRC_MASK) * 32 + col];
        __half2 x3 = cur[(long long)(ea.w & SRC_MASK) * 32 + col];
        float w0 = (float)(ea.x >> 19) * W_SCALE;
        float w1 = (float)(ea.y >> 19) * W_SCALE;
        float w2 = (float)(ea.z >> 19) * W_SCALE;
        float w3 = (float)(ea.w >> 19) * W_SCALE;
        float2 f0 = __half22float2(x0);
        float2 f1 = __half22float2(x1);
        float2 f2 = __half22float2(x2);
        float2 f3 = __half22float2(x3);
        accx = fmaf(w0, f0.x, accx); accy = fmaf(w0, f0.y, accy);
        bccx = fmaf(w1, f1.x, bccx); bccy = fmaf(w1, f1.y, bccy);
        accx = fmaf(w2, f2.x, accx); accy = fmaf(w2, f2.y, accy);
        bccx = fmaf(w3, f3.x, bccx); bccy = fmaf(w3, f3.y, bccy);
    }
    for (; i < n; ++i) {
        unsigned e0 = sl[i];
        __half2 x0 = cur[(long long)(e0 & SRC_MASK) * 32 + col];
        float w0 = (float)(e0 >> 19) * W_SCALE;
        float2 f0 = __half22float2(x0);
        accx = fmaf(w0, f0.x, accx); accy = fmaf(w0, f0.y, accy);
    }
    accx += bccx; accy += bccy;
    long long oi = (long long)node * 32 + col;
    if (!LAST) {
        __half2 h; h.x = __float2half_rn(accx); h.y = __float2half_rn(accy);
        next[oi] = h;
    } else {
        float2 f0 = __half22float2(x0b[oi]);
        float2 f1 = __half22float2(x1b[oi]);
        float2 f2 = __half22float2(cur[oi]);
        float2 o;
        o.x = (f0.x + f1.x + f2.x + accx) * 0.25f;
        o.y = (f0.y + f1.y + f2.y + accy) * 0.25f;
        out[oi] = o;
    }
}

// ---------------------------------------------------------------- launch
extern "C" void kernel_launch(void* const* d_in, const int* in_sizes, int n_in,
                              void* d_out, int out_size, void* d_ws, size_t ws_size,
                              hipStream_t stream) {
    const float* user_emb = (const float*)d_in[0];
    const float* item_emb = (const float*)d_in[1];
    const float* ew       = (const float*)d_in[2];
    const int*   es       = (const int*)d_in[3];
    const int*   ed       = (const int*)d_in[4];
    float* out = (float*)d_out;

    // ws layout:
    //   slots    u32 x N_NODES*CAP       [0          .. 115,200,000)
    //   deg      int x N_NODES           [115.2M     .. 116,400,000)
    //   buf0     fp16 x NELEM  (x0)      [116.4M     .. 154,800,000)
    //   buf1     fp16 x NELEM  (x1)      [154.8M     .. 193,200,000)
    //   buf2     fp16 x NELEM  (x2)      [193.2M     .. 231,600,000)
    //   blk_info u32 x NBINS*NBLK_A      [231.6M     .. 233,170,480)
    //   seg      u64 x NBLK_A*EPB overlays buf0..buf2-head (dead before init)
    // max ~233.2 MB (prior sessions verified 235 MB fits). seg/blk_info are
    // produced by binA, consumed by binB; buf0 is written by init AFTER binB
    // and buf2 first written by layer 2 — stream order makes overlays safe.
    unsigned* slots = (unsigned*)d_ws;
    int*      deg   = (int*)(slots + (long long)N_NODES * CAP);
    __half*   buf0  = (__half*)(deg + N_NODES);
    __half*   buf1  = buf0 + NELEM;
    __half*   buf2  = buf1 + NELEM;
    unsigned* blk_info = (unsigned*)(buf2 + NELEM);
    unsigned long long* seg = (unsigned long long*)buf0;

    const int B = 256;
    const long long node_waves  = (N_NODES + 1) / 2;                       // 150000
    const long long node_blocks = (node_waves * 64 + B - 1) / B;           // 37500
    const long long init_blocks = (NELEM4 + B - 1) / B;

    // ---- LDS-staged binned bucket build (no global atomics, no memset) ----
    binA_kernel<<<dim3((unsigned)NBLK_A), dim3(512), 0, stream>>>(
        es, ed, ew, seg, blk_info);
    binB_kernel<<<dim3((unsigned)NBINS), dim3(512), 0, stream>>>(
        blk_info, seg, deg, slots);

    // cur = fp16(all_emb). After binB (seg overlay).
    init_kernel<<<dim3((unsigned)init_blocks), dim3(B), 0, stream>>>(
        (const float4*)user_emb, (const float4*)item_emb, (ushort4*)buf0);

    // ---- 3 gather layers; final mean fused into layer 3 ----
    spmm_gather<false><<<dim3((unsigned)node_blocks), dim3(B), 0, stream>>>(
        deg, slots, (const __half2*)buf0, (__half2*)buf1,
        nullptr, nullptr, nullptr);
    spmm_gather<false><<<dim3((unsigned)node_blocks), dim3(B), 0, stream>>>(
        deg, slots, (const __half2*)buf1, (__half2*)buf2,
        nullptr, nullptr, nullptr);
    spmm_gather<true><<<dim3((unsigned)node_blocks), dim3(B), 0, stream>>>(
        deg, slots, (const __half2*)buf2, nullptr,
        (const __half2*)buf0, (const __half2*)buf1, (float2*)out);
}